// Round 2
// baseline (111.082 us; speedup 1.0000x reference)
//
#include <hip/hip_runtime.h>

// Shapes fixed by setup_inputs: B=4, D=20, H=W=128, HW=16384, K=65536 voxels.
// Decomposition: 4 slices (waves) per voxel group; each block = 64 voxels x 4 slices.
// Slice s computes src rows i = s*5 .. s*5+4; d2s/srcA/locmax combined via LDS.
#define HW   16384
#define NS   4
#define ROWS 5
#define VPB  64

__global__ __launch_bounds__(256, 4) void chamfer_main(
    const float* __restrict__ pred,   // [B, 60, HW]  channel c*20+i
    const float* __restrict__ gt,     // [B, 60, HW]  channel j*3+c
    const float* __restrict__ cmask,  // [B, 20, HW]
    const float* __restrict__ vmask,  // [B, HW]
    const float* __restrict__ pnum,   // [B, HW]
    const float* __restrict__ gnum,   // [B, HW]
    float* __restrict__ ws)
{
    const int lane = threadIdx.x & 63;   // voxel within block
    const int s    = threadIdx.x >> 6;   // slice (wave id)
    const int k    = blockIdx.x * VPB + lane;
    const int b    = k >> 14;            // k / HW
    const int hw   = k & (HW - 1);       // k % HW
    const size_t pbase = (size_t)b * 60 * HW + hw;
    const size_t cbase = (size_t)b * 20 * HW + hw;

    // dst points: dst[3*j+c] = gt[b, j*3+c, hw] (redundant per slice; L1-cached)
    float dst[60];
    #pragma unroll
    for (int t = 0; t < 60; ++t) dst[t] = gt[pbase + (size_t)t * HW];

    unsigned cmbits = 0u;
    #pragma unroll
    for (int j = 0; j < 20; ++j)
        if (cmask[cbase + (size_t)j * HW] > 0.f) cmbits |= (1u << j);
    // row-min selection: masked j if any masked, else all j (then + max_d later)
    const unsigned selbits = cmbits ? cmbits : 0xFFFFFu;

    const float INF = __int_as_float(0x7f800000);
    float d2s[20];
    #pragma unroll
    for (int j = 0; j < 20; ++j) d2s[j] = INF;

    float srcA = 0.f, locmax = 0.f;
    #pragma unroll
    for (int r = 0; r < ROWS; ++r) {
        const int i = s * ROWS + r;
        float sx = pred[pbase + (size_t)i        * HW];
        float sy = pred[pbase + (size_t)(20 + i) * HW];
        float sz = pred[pbase + (size_t)(40 + i) * HW];
        float rm = INF;
        #pragma unroll
        for (int j = 0; j < 20; ++j) {
            float d = fabsf(sx - dst[3*j]) + fabsf(sy - dst[3*j+1]) + fabsf(sz - dst[3*j+2]);
            locmax = fmaxf(locmax, d);
            d2s[j] = fminf(d2s[j], d);
            rm     = fminf(rm, ((selbits >> j) & 1u) ? d : INF);
        }
        srcA += rm;
    }

    // cross-slice combine via LDS (stride 21 -> conflict-free)
    __shared__ float l_d2s[NS][VPB][21];
    __shared__ float l_sa[NS][VPB];
    __shared__ float l_mx[NS][VPB];
    #pragma unroll
    for (int j = 0; j < 20; ++j) l_d2s[s][lane][j] = d2s[j];
    l_sa[s][lane] = srcA;
    l_mx[s][lane] = locmax;
    __syncthreads();

    if (s == 0) {
        float sa = 0.f, mx = 0.f;
        #pragma unroll
        for (int t = 0; t < NS; ++t) {
            sa += l_sa[t][lane];
            mx = fmaxf(mx, l_mx[t][lane]);
        }
        float dsum = 0.f;
        #pragma unroll
        for (int j = 0; j < 20; ++j) {
            float m = fminf(fminf(l_d2s[0][lane][j], l_d2s[1][lane][j]),
                            fminf(l_d2s[2][lane][j], l_d2s[3][lane][j]));
            if ((cmbits >> j) & 1u) dsum += m;
        }
        const float vw = vmask[k];
        float vals[7];
        vals[0] = sa * vw;                                   // src-loss min-sum
        vals[1] = (cmbits == 0u) ? 20.f * vw : 0.f;          // rows needing +max_d
        vals[2] = dsum * vw;                                 // dst-loss numerator
        vals[3] = vw * (float)__popc(cmbits);                // dst-loss denominator
        float diff = pnum[k] - gnum[k];
        float ad = fabsf(diff);
        vals[4] = ((ad < 1.f) ? 0.5f * diff * diff : (ad - 0.5f)) * vw;
        vals[5] = vw;                                        // wsum
        vals[6] = (vw > 0.f) ? mx : 0.f;                     // masked max

        #pragma unroll
        for (int off = 32; off > 0; off >>= 1) {
            #pragma unroll
            for (int v = 0; v < 6; ++v) vals[v] += __shfl_down(vals[v], off);
            vals[6] = fmaxf(vals[6], __shfl_down(vals[6], off));
        }
        if (lane == 0) {
            #pragma unroll
            for (int v = 0; v < 6; ++v) atomicAdd(&ws[v], vals[v]);
            atomicMax((int*)&ws[6], __float_as_int(vals[6]));  // dist>=0: int max == float max
        }
    }
}

__global__ void chamfer_fin(const float* __restrict__ ws, float* __restrict__ out)
{
    const float maxd   = ws[6];
    const float wsum   = ws[5];
    const float loss_s = (ws[0] + ws[1] * maxd) / (wsum * 20.f);
    const float loss_d = ws[2] / ws[3];
    const float numl   = ws[4] / ws[5];
    out[0] = loss_s + loss_d + 0.1f * numl;
}

extern "C" void kernel_launch(void* const* d_in, const int* in_sizes, int n_in,
                              void* d_out, int out_size, void* d_ws, size_t ws_size,
                              hipStream_t stream)
{
    const float* pred  = (const float*)d_in[0];
    const float* gt    = (const float*)d_in[1];
    const float* cmask = (const float*)d_in[2];
    const float* vmask = (const float*)d_in[3];
    const float* pnum  = (const float*)d_in[4];
    const float* gnum  = (const float*)d_in[5];
    float* out = (float*)d_out;
    float* ws  = (float*)d_ws;

    const int nvox = in_sizes[3];            // B*H*W = 65536
    hipMemsetAsync(ws, 0, 8 * sizeof(float), stream);
    chamfer_main<<<nvox / VPB, NS * VPB, 0, stream>>>(pred, gt, cmask, vmask, pnum, gnum, ws);
    chamfer_fin<<<1, 1, 0, stream>>>(ws, out);
}

// Round 3
// 108.453 us; speedup vs baseline: 1.0242x; 1.0242x over previous
//
#include <hip/hip_runtime.h>

// Shapes fixed by setup_inputs: B=4, D=20, H=W=128, HW=16384, K=65536 voxels.
// Decomposition: block = 64 voxels x 4 wave-slices. Slice s owns dst points
// j = s*5..s*5+4 (15 regs) and all 20 src rows; rm[20] (per-row masked min)
// is the only persistent array; cross-slice combine via LDS.
#define HW   16384
#define NS   4
#define JC   5
#define VPB  64

__global__ __launch_bounds__(256, 4) void chamfer_main(
    const float* __restrict__ pred,   // [B, 60, HW]  channel c*20+i
    const float* __restrict__ gt,     // [B, 60, HW]  channel j*3+c
    const float* __restrict__ cmask,  // [B, 20, HW]
    const float* __restrict__ vmask,  // [B, HW]
    const float* __restrict__ pnum,   // [B, HW]
    const float* __restrict__ gnum,   // [B, HW]
    float* __restrict__ ws)
{
    const int lane = threadIdx.x & 63;   // voxel within block
    const int s    = threadIdx.x >> 6;   // slice (wave id)
    const int k    = blockIdx.x * VPB + lane;
    const int b    = k >> 14;
    const int hw   = k & (HW - 1);
    const size_t pbase = (size_t)b * 60 * HW + hw;
    const size_t cbase = (size_t)b * 20 * HW + hw;

    // chamfer-mask bits (all 20; redundant across slices, L1-cached)
    unsigned cmbits = 0u;
    #pragma unroll
    for (int j = 0; j < 20; ++j)
        if (cmask[cbase + (size_t)j * HW] > 0.f) cmbits |= (1u << j);
    // row-min selection: masked j if any masked, else all j (then + max_d later)
    const unsigned selbits = cmbits ? cmbits : 0xFFFFFu;

    // own dst chunk: j = j0..j0+4
    const int j0 = s * JC;
    float dx[JC], dy[JC], dz[JC];
    #pragma unroll
    for (int r = 0; r < JC; ++r) {
        const int j = j0 + r;
        dx[r] = gt[pbase + (size_t)(3*j    ) * HW];
        dy[r] = gt[pbase + (size_t)(3*j + 1) * HW];
        dz[r] = gt[pbase + (size_t)(3*j + 2) * HW];
    }

    const float INF = __int_as_float(0x7f800000);
    float d2sc[JC];
    #pragma unroll
    for (int r = 0; r < JC; ++r) d2sc[r] = INF;
    float rm[20];
    #pragma unroll
    for (int i = 0; i < 20; ++i) rm[i] = INF;

    float locmax = 0.f;
    #pragma unroll   // FULL unroll: keeps rm[i] statically indexed (no scratch)
    for (int i = 0; i < 20; ++i) {
        const float sx = pred[pbase + (size_t)(i)      * HW];
        const float sy = pred[pbase + (size_t)(20 + i) * HW];
        const float sz = pred[pbase + (size_t)(40 + i) * HW];
        #pragma unroll
        for (int r = 0; r < JC; ++r) {
            float d = fabsf(sx - dx[r]) + fabsf(sy - dy[r]) + fabsf(sz - dz[r]);
            locmax  = fmaxf(locmax, d);
            d2sc[r] = fminf(d2sc[r], d);
            rm[i]   = fminf(rm[i], ((selbits >> (j0 + r)) & 1u) ? d : INF);
        }
    }

    // local masked d2s partial sum (scalar)
    float dsum = 0.f;
    #pragma unroll
    for (int r = 0; r < JC; ++r)
        if ((cmbits >> (j0 + r)) & 1u) dsum += d2sc[r];

    // cross-slice combine via LDS (stride 21 -> odd stride, conflict-free)
    __shared__ float l_rm[NS][VPB][21];
    __shared__ float l_ds[NS][VPB];
    __shared__ float l_mx[NS][VPB];
    #pragma unroll
    for (int i = 0; i < 20; ++i) l_rm[s][lane][i] = rm[i];
    l_ds[s][lane] = dsum;
    l_mx[s][lane] = locmax;
    __syncthreads();

    if (s == 0) {
        float srcA = 0.f;
        #pragma unroll
        for (int i = 0; i < 20; ++i) {
            float m = fminf(fminf(l_rm[0][lane][i], l_rm[1][lane][i]),
                            fminf(l_rm[2][lane][i], l_rm[3][lane][i]));
            srcA += m;
        }
        const float dall = l_ds[0][lane] + l_ds[1][lane] + l_ds[2][lane] + l_ds[3][lane];
        const float mx   = fmaxf(fmaxf(l_mx[0][lane], l_mx[1][lane]),
                                 fmaxf(l_mx[2][lane], l_mx[3][lane]));
        const float vw = vmask[k];
        float vals[7];
        vals[0] = srcA * vw;                          // src-loss min-sum
        vals[1] = (cmbits == 0u) ? 20.f * vw : 0.f;   // rows needing +max_d
        vals[2] = dall * vw;                          // dst-loss numerator
        vals[3] = vw * (float)__popc(cmbits);         // dst-loss denominator
        const float diff = pnum[k] - gnum[k];
        const float ad = fabsf(diff);
        vals[4] = ((ad < 1.f) ? 0.5f * diff * diff : (ad - 0.5f)) * vw;
        vals[5] = vw;                                 // wsum
        vals[6] = (vw > 0.f) ? mx : 0.f;              // masked max

        #pragma unroll
        for (int off = 32; off > 0; off >>= 1) {
            #pragma unroll
            for (int v = 0; v < 6; ++v) vals[v] += __shfl_down(vals[v], off);
            vals[6] = fmaxf(vals[6], __shfl_down(vals[6], off));
        }
        if (lane == 0) {
            #pragma unroll
            for (int v = 0; v < 6; ++v) atomicAdd(&ws[v], vals[v]);
            atomicMax((int*)&ws[6], __float_as_int(vals[6]));  // dist>=0: int max == float max
        }
    }
}

__global__ void chamfer_fin(const float* __restrict__ ws, float* __restrict__ out)
{
    const float maxd   = ws[6];
    const float wsum   = ws[5];
    const float loss_s = (ws[0] + ws[1] * maxd) / (wsum * 20.f);
    const float loss_d = ws[2] / ws[3];
    const float numl   = ws[4] / ws[5];
    out[0] = loss_s + loss_d + 0.1f * numl;
}

extern "C" void kernel_launch(void* const* d_in, const int* in_sizes, int n_in,
                              void* d_out, int out_size, void* d_ws, size_t ws_size,
                              hipStream_t stream)
{
    const float* pred  = (const float*)d_in[0];
    const float* gt    = (const float*)d_in[1];
    const float* cmask = (const float*)d_in[2];
    const float* vmask = (const float*)d_in[3];
    const float* pnum  = (const float*)d_in[4];
    const float* gnum  = (const float*)d_in[5];
    float* out = (float*)d_out;
    float* ws  = (float*)d_ws;

    const int nvox = in_sizes[3];            // B*H*W = 65536
    hipMemsetAsync(ws, 0, 8 * sizeof(float), stream);
    chamfer_main<<<nvox / VPB, NS * VPB, 0, stream>>>(pred, gt, cmask, vmask, pnum, gnum, ws);
    chamfer_fin<<<1, 1, 0, stream>>>(ws, out);
}

// Round 4
// 106.759 us; speedup vs baseline: 1.0405x; 1.0159x over previous
//
#include <hip/hip_runtime.h>

// Shapes fixed by setup_inputs: B=4, D=20, H=W=128, HW=16384, K=65536 voxels.
// Block = 64 voxels (lane) x 8 waves. Wave w=(si<<1)|sj owns the 5x10
// sub-matrix: src rows i=si*5..+4, dst cols j=sj*10..+9. Per-thread state is
// small (~65 VGPR) so loads keep high memory-level parallelism. Cross-wave
// combine of row-mins / col-mins via LDS; wave 0 finalizes per voxel.
#define HW  16384
#define VPB 64
#define NW  8

__global__ __launch_bounds__(512, 6) void chamfer_main(
    const float* __restrict__ pred,   // [B, 60, HW]  channel c*20+i
    const float* __restrict__ gt,     // [B, 60, HW]  channel j*3+c
    const float* __restrict__ cmask,  // [B, 20, HW]
    const float* __restrict__ vmask,  // [B, HW]
    const float* __restrict__ pnum,   // [B, HW]
    const float* __restrict__ gnum,   // [B, HW]
    float* __restrict__ ws)
{
    const int lane = threadIdx.x & 63;   // voxel within block
    const int w    = threadIdx.x >> 6;   // wave 0..7
    const int si   = w >> 1;             // src-row group (5 rows)
    const int sj   = w & 1;              // dst-col group (10 cols)
    const int k    = blockIdx.x * VPB + lane;
    const int b    = k >> 14;
    const int hw   = k & (HW - 1);
    const size_t pbase = (size_t)b * 60 * HW + hw;
    const size_t cbase = (size_t)b * 20 * HW + hw;
    const int j0 = sj * 10;
    const int i0 = si * 5;

    // my half of the chamfer-mask bits (bit position = global j)
    unsigned mybits = 0u;
    #pragma unroll
    for (int jj = 0; jj < 10; ++jj)
        if (cmask[cbase + (size_t)(j0 + jj) * HW] > 0.f) mybits |= 1u << (j0 + jj);

    // my 10 dst points (independent load batch -> full MLP)
    float dx[10], dy[10], dz[10];
    #pragma unroll
    for (int jj = 0; jj < 10; ++jj) {
        dx[jj] = gt[pbase + (size_t)(3*(j0+jj)    ) * HW];
        dy[jj] = gt[pbase + (size_t)(3*(j0+jj) + 1) * HW];
        dz[jj] = gt[pbase + (size_t)(3*(j0+jj) + 2) * HW];
    }

    const float INF = __int_as_float(0x7f800000);
    float d2s[10], rmm[5], rma[5];
    #pragma unroll
    for (int jj = 0; jj < 10; ++jj) d2s[jj] = INF;
    #pragma unroll
    for (int r = 0; r < 5; ++r) { rmm[r] = INF; rma[r] = INF; }

    float locmax = 0.f;
    #pragma unroll
    for (int r = 0; r < 5; ++r) {
        const int i = i0 + r;
        const float sx = pred[pbase + (size_t)(i)      * HW];
        const float sy = pred[pbase + (size_t)(20 + i) * HW];
        const float sz = pred[pbase + (size_t)(40 + i) * HW];
        #pragma unroll
        for (int jj = 0; jj < 10; ++jj) {
            float d = fabsf(sx - dx[jj]) + fabsf(sy - dy[jj]) + fabsf(sz - dz[jj]);
            locmax  = fmaxf(locmax, d);
            d2s[jj] = fminf(d2s[jj], d);
            rma[r]  = fminf(rma[r], d);
            rmm[r]  = fminf(rmm[r], ((mybits >> (j0 + jj)) & 1u) ? d : INF);
        }
    }

    // cross-wave combine via LDS. Lane stride 10 dwords -> 2-way bank alias (free).
    __shared__ float    l_rm [NW][VPB][10];  // [0..4]=masked min, [5..9]=all min
    __shared__ float    l_d2s[NW][VPB][10];
    __shared__ float    l_mx [NW][VPB];
    __shared__ unsigned l_bits[2][VPB];
    #pragma unroll
    for (int r = 0; r < 5; ++r) { l_rm[w][lane][r] = rmm[r]; l_rm[w][lane][5 + r] = rma[r]; }
    #pragma unroll
    for (int jj = 0; jj < 10; ++jj) l_d2s[w][lane][jj] = d2s[jj];
    l_mx[w][lane] = locmax;
    if (si == 0) l_bits[sj][lane] = mybits;
    __syncthreads();

    if (w == 0) {
        const int v = lane;
        const unsigned cmbits = l_bits[0][v] | l_bits[1][v];
        const int off = cmbits ? 0 : 5;           // masked mins vs all-j mins
        float srcA = 0.f;
        #pragma unroll
        for (int i = 0; i < 20; ++i) {
            const int ww = (i / 5) * 2, r = i % 5;
            srcA += fminf(l_rm[ww][v][r + off], l_rm[ww + 1][v][r + off]);
        }
        float dsum = 0.f;
        #pragma unroll
        for (int j = 0; j < 20; ++j) {
            const int sjj = j / 10, jj = j % 10;
            float m = fminf(fminf(l_d2s[0 + sjj][v][jj], l_d2s[2 + sjj][v][jj]),
                            fminf(l_d2s[4 + sjj][v][jj], l_d2s[6 + sjj][v][jj]));
            dsum += ((cmbits >> j) & 1u) ? m : 0.f;
        }
        float mx = 0.f;
        #pragma unroll
        for (int t = 0; t < NW; ++t) mx = fmaxf(mx, l_mx[t][v]);

        const float vw = vmask[k];
        float vals[7];
        vals[0] = srcA * vw;                          // src-loss min-sum
        vals[1] = (cmbits == 0u) ? 20.f * vw : 0.f;   // rows needing +max_d
        vals[2] = dsum * vw;                          // dst-loss numerator
        vals[3] = vw * (float)__popc(cmbits);         // dst-loss denominator
        const float diff = pnum[k] - gnum[k];
        const float ad = fabsf(diff);
        vals[4] = ((ad < 1.f) ? 0.5f * diff * diff : (ad - 0.5f)) * vw;
        vals[5] = vw;                                 // wsum
        vals[6] = (vw > 0.f) ? mx : 0.f;              // masked max

        #pragma unroll
        for (int o = 32; o > 0; o >>= 1) {
            #pragma unroll
            for (int x = 0; x < 6; ++x) vals[x] += __shfl_down(vals[x], o);
            vals[6] = fmaxf(vals[6], __shfl_down(vals[6], o));
        }
        if (lane == 0) {
            #pragma unroll
            for (int x = 0; x < 6; ++x) atomicAdd(&ws[x], vals[x]);
            atomicMax((int*)&ws[6], __float_as_int(vals[6]));  // dist>=0: int max == float max
        }
    }
}

__global__ void chamfer_fin(const float* __restrict__ ws, float* __restrict__ out)
{
    const float maxd   = ws[6];
    const float wsum   = ws[5];
    const float loss_s = (ws[0] + ws[1] * maxd) / (wsum * 20.f);
    const float loss_d = ws[2] / ws[3];
    const float numl   = ws[4] / ws[5];
    out[0] = loss_s + loss_d + 0.1f * numl;
}

extern "C" void kernel_launch(void* const* d_in, const int* in_sizes, int n_in,
                              void* d_out, int out_size, void* d_ws, size_t ws_size,
                              hipStream_t stream)
{
    const float* pred  = (const float*)d_in[0];
    const float* gt    = (const float*)d_in[1];
    const float* cmask = (const float*)d_in[2];
    const float* vmask = (const float*)d_in[3];
    const float* pnum  = (const float*)d_in[4];
    const float* gnum  = (const float*)d_in[5];
    float* out = (float*)d_out;
    float* ws  = (float*)d_ws;

    const int nvox = in_sizes[3];            // B*H*W = 65536
    hipMemsetAsync(ws, 0, 8 * sizeof(float), stream);
    chamfer_main<<<nvox / VPB, NW * 64, 0, stream>>>(pred, gt, cmask, vmask, pnum, gnum, ws);
    chamfer_fin<<<1, 1, 0, stream>>>(ws, out);
}